// Round 4
// baseline (454.978 us; speedup 1.0000x reference)
//
#include <hip/hip_runtime.h>

typedef float  f32x4  __attribute__((ext_vector_type(4)));
typedef float  f32x16 __attribute__((ext_vector_type(16)));
typedef short  s16x8  __attribute__((ext_vector_type(8)));
typedef unsigned short u16x4 __attribute__((ext_vector_type(4)));

#define AS1 __attribute__((address_space(1)))
#define AS3 __attribute__((address_space(3)))

__device__ __forceinline__ unsigned short f2bf(float x){
    union { float f; unsigned int u; } v; v.f = x;
    unsigned int r = v.u + 0x7FFFu + ((v.u >> 16) & 1u);   // RNE
    return (unsigned short)(r >> 16);
}

__device__ __forceinline__ void gload16(const unsigned short* g, const char* l){
    __builtin_amdgcn_global_load_lds((const AS1 void*)g, (AS3 void*)l, 16, 0, 0);
}

__device__ __forceinline__ void mfma32(f32x16& c, s16x8 a, s16x8 b){
    asm volatile("v_mfma_f32_32x32x16_bf16 %0, %1, %2, %0" : "+v"(c) : "v"(a), "v"(b));
}

#define GBAR() do{ asm volatile("" ::: "memory"); __builtin_amdgcn_s_barrier(); \
                   asm volatile("" ::: "memory"); }while(0)

// ---------------------------------------------------------------------------
// Row l2-normalize [rows][1024] f32 -> bf16. One 256-thread block per row.
// ---------------------------------------------------------------------------
__global__ __launch_bounds__(256) void norm_rows_bf16(const float* __restrict__ in,
                                                      unsigned short* __restrict__ out){
    const int row = blockIdx.x;
    const int t   = threadIdx.x;
    f32x4 x = ((const f32x4*)(in + (size_t)row * 1024))[t];
    float ss = x[0]*x[0] + x[1]*x[1] + x[2]*x[2] + x[3]*x[3];
    #pragma unroll
    for (int o = 32; o > 0; o >>= 1) ss += __shfl_xor(ss, o);
    __shared__ float red[4];
    if ((t & 63) == 0) red[t >> 6] = ss;
    __syncthreads();
    float tot = red[0] + red[1] + red[2] + red[3];
    float inv = 1.0f / fmaxf(sqrtf(tot), 1e-12f);
    u16x4 o;
    #pragma unroll
    for (int j = 0; j < 4; ++j) o[j] = f2bf(x[j] * inv);
    ((u16x4*)(out + (size_t)row * 1024))[t] = o;
}

// ---------------------------------------------------------------------------
// Final in-place row l2-normalize of d_out [N][1024] f32.
// ---------------------------------------------------------------------------
__global__ __launch_bounds__(256) void norm_rows_f32(float* __restrict__ buf){
    const int row = blockIdx.x;
    const int t   = threadIdx.x;
    f32x4* p = (f32x4*)(buf + (size_t)row * 1024);
    f32x4 x = p[t];
    float ss = x[0]*x[0] + x[1]*x[1] + x[2]*x[2] + x[3]*x[3];
    #pragma unroll
    for (int o = 32; o > 0; o >>= 1) ss += __shfl_xor(ss, o);
    __shared__ float red[4];
    if ((t & 63) == 0) red[t >> 6] = ss;
    __syncthreads();
    float tot = red[0] + red[1] + red[2] + red[3];
    float inv = 1.0f / fmaxf(sqrtf(tot), 1e-12f);
    p[t] = x * inv;
}

// ---------------------------------------------------------------------------
// offset [C=2048][D=1024] f32 -> offt [D][C] bf16 (LDS-tiled transpose),
// fused sum(offset^2) -> atomicAdd(reg_out). Tile: 64(c) x 64(d).
// ---------------------------------------------------------------------------
__global__ __launch_bounds__(256) void transpose_off(const float* __restrict__ off,
                                                     unsigned short* __restrict__ offt,
                                                     float* __restrict__ reg_out){
    __shared__ unsigned short t_lds[64][68];   // [d][c], padded row
    const int t  = threadIdx.x;
    const int c0 = blockIdx.x * 64;
    const int d0 = blockIdx.y * 64;
    float ss = 0.f;
    #pragma unroll
    for (int p = 0; p < 4; ++p){
        int c  = p * 16 + (t >> 4);
        int dq = t & 15;
        f32x4 v = *(const f32x4*)(off + (size_t)(c0 + c) * 1024 + d0 + dq * 4);
        ss += v[0]*v[0] + v[1]*v[1] + v[2]*v[2] + v[3]*v[3];
        #pragma unroll
        for (int j = 0; j < 4; ++j) t_lds[dq * 4 + j][c] = f2bf(v[j]);
    }
    __syncthreads();
    #pragma unroll
    for (int p = 0; p < 4; ++p){
        int d  = p * 16 + (t >> 4);
        int cq = t & 15;
        u16x4 o = *(const u16x4*)&t_lds[d][cq * 4];
        *(u16x4*)(offt + (size_t)(d0 + d) * 2048 + c0 + cq * 4) = o;
    }
    #pragma unroll
    for (int o = 32; o > 0; o >>= 1) ss += __shfl_xor(ss, o);
    __shared__ float red[4];
    if ((t & 63) == 0) red[t >> 6] = ss;
    __syncthreads();
    if (t == 0) atomicAdd(reg_out, red[0] + red[1] + red[2] + red[3]);
}

// ---------------------------------------------------------------------------
// GEMM: acc[m][n] = sum_k A[m][k] * B[n][k]   (both bf16, K-contiguous rows)
// 256x256 tile, BK=64, 512 threads (8 waves, 2Mx4N; wave tile 128x64).
// 32x32x16 bf16 MFMA (4 m-frags x 2 n-frags x 4 ks).
// Double-buffered 128 KiB LDS; buffer = [Ak0|Bk0|Ak1|Bk1] 16KB K-half blocks
// (256 rows x 32 k, 64B rows, XOR granule swizzle g ^= (row>>1)&3 applied via
// pre-swizzled global source + swizzled ds_read; measured 0 conflicts).
// 2 half-phases / K-tile: {12 ds_read (2 ks) | stage 2 quarters} -> barrier
// -> 16 MFMA (compiler counted lgkmcnt) -> vmcnt(4) -> barrier.
// Loads stay in flight across barriers; vmcnt never 0 in steady state.
// EPI==1: Wout[m][n] = bf16(exp(10*acc - 10))        (ld = ldw)
// EPI==2: Fout[m][n] = Cadd[m][n] + acc              (ld = ldo)
// ---------------------------------------------------------------------------
template<int EPI>
__global__ __launch_bounds__(512, 2)
void gemm256(const unsigned short* __restrict__ A, int lda,
             const unsigned short* __restrict__ B, int ldb,
             int K,
             unsigned short* __restrict__ Wout, int ldw,
             const float* __restrict__ Cadd, float* __restrict__ Fout, int ldo)
{
    extern __shared__ char smem[];             // 2 x 64 KiB
    const int tid  = threadIdx.x;
    const int m0   = blockIdx.x * 256;
    const int n0   = blockIdx.y * 256;
    const int wid  = tid >> 6, lane = tid & 63;
    const int wr   = wid >> 2, wc = wid & 3;   // 2 x 4 waves, wave tile 128x64
    const int l31  = lane & 31, hg = lane >> 5;

    // ---- staging: per 16KB quarter-block, thread covers phys bytes tid*16
    // and 8192+tid*16; phys granule (tid&3) at row tid>>2 (and +128) holds
    // logical granule (tid&3)^((row>>1)&3) -> pre-swizzled global source.
    const int srow = tid >> 2;
    const int sg   = (tid & 3) ^ ((tid >> 3) & 3);
    const unsigned short* sA0 = A + (size_t)(m0 + srow)       * lda + sg * 8;
    const unsigned short* sA1 = A + (size_t)(m0 + 128 + srow) * lda + sg * 8;
    const unsigned short* sB0 = B + (size_t)(n0 + srow)       * ldb + sg * 8;
    const unsigned short* sB1 = B + (size_t)(n0 + 128 + srow) * ldb + sg * 8;
    const int lp0 = tid * 16, lp1 = 8192 + tid * 16;

    auto stageA = [&](char* wb, int blk, int ke){
        gload16(sA0 + ke, wb + blk * 16384 + lp0);
        gload16(sA1 + ke, wb + blk * 16384 + lp1);
    };
    auto stageB = [&](char* wb, int blk, int ke){
        gload16(sB0 + ke, wb + blk * 16384 + lp0);
        gload16(sB1 + ke, wb + blk * 16384 + lp1);
    };

    // ---- ds_read fragment offsets within a K-half block (swizzled) ----
    // frag: 32 rows x 16 k; lane row = base + l31, k-granule = ksl*2 + hg
    int aoff[2][4], boff[2][2];
    #pragma unroll
    for (int ksl = 0; ksl < 2; ++ksl){
        #pragma unroll
        for (int m = 0; m < 4; ++m){
            int row = wr * 128 + m * 32 + l31;
            int g   = (ksl * 2 + hg) ^ ((row >> 1) & 3);
            aoff[ksl][m] = row * 64 + g * 16;
        }
        #pragma unroll
        for (int n = 0; n < 2; ++n){
            int row = wc * 64 + n * 32 + l31;
            int g   = (ksl * 2 + hg) ^ ((row >> 1) & 3);
            boff[ksl][n] = 16384 + row * 64 + g * 16;
        }
    }

    f32x16 acc[4][2] = {};
    const int nsteps = K >> 6;                 // BK = 64

    // ---- prologue: stage tile 0 fully ----
    {
        char* wb = smem;
        stageA(wb, 0, 0);  stageB(wb, 1, 0);
        stageA(wb, 2, 32); stageB(wb, 3, 32);
    }
    asm volatile("s_waitcnt vmcnt(4)" ::: "memory");   // Ak0,Bk0(t0) landed
    GBAR();

    // One half-phase: 12 frag reads (ks pair), STAGES, barrier, 16 MFMA
    // (compiler emits counted lgkmcnt off reg deps), vmcnt(VMN), barrier.
#define HALFSTEP(rb_, half_, STAGES, VMN) do{                                  \
    const char* hb_ = (rb_) + (half_) * 32768;                                 \
    s16x8 ax[4], bx[2], ay[4], by[2];                                          \
    _Pragma("unroll") for (int m = 0; m < 4; ++m)                              \
        ax[m] = *(const s16x8*)(hb_ + aoff[0][m]);                             \
    _Pragma("unroll") for (int n = 0; n < 2; ++n)                              \
        bx[n] = *(const s16x8*)(hb_ + boff[0][n]);                             \
    _Pragma("unroll") for (int m = 0; m < 4; ++m)                              \
        ay[m] = *(const s16x8*)(hb_ + aoff[1][m]);                             \
    _Pragma("unroll") for (int n = 0; n < 2; ++n)                              \
        by[n] = *(const s16x8*)(hb_ + boff[1][n]);                             \
    STAGES;                                                                    \
    GBAR();                                                                    \
    __builtin_amdgcn_s_setprio(1);                                             \
    _Pragma("unroll") for (int m = 0; m < 4; ++m)                              \
    _Pragma("unroll") for (int n = 0; n < 2; ++n)                              \
        mfma32(acc[m][n], ax[m], bx[n]);                                       \
    _Pragma("unroll") for (int m = 0; m < 4; ++m)                              \
    _Pragma("unroll") for (int n = 0; n < 2; ++n)                              \
        mfma32(acc[m][n], ay[m], by[n]);                                       \
    __builtin_amdgcn_s_setprio(0);                                             \
    asm volatile("s_waitcnt vmcnt(" #VMN ")" ::: "memory");                    \
    GBAR();                                                                    \
}while(0)

    #pragma unroll 1
    for (int t = 0; t < nsteps - 1; ++t){
        const char* rb = smem + (t & 1) * 65536;
        char*       wb = smem + ((t + 1) & 1) * 65536;
        const int   ke = (t + 1) * 64;
        // H0: compute Khalf0(t); stage Ak0,Bk0(t+1); wait: Ak1,Bk1(t) landed
        HALFSTEP(rb, 0, { stageA(wb, 0, ke); stageB(wb, 1, ke); }, 4);
        // H1: compute Khalf1(t); stage Ak1,Bk1(t+1); wait: Ak0,Bk0(t+1) landed
        HALFSTEP(rb, 1, { stageA(wb, 2, ke + 32); stageB(wb, 3, ke + 32); }, 4);
    }
    {   // ---- last K-tile: no staging; drain Ak1,Bk1(last) before H1 reads
        const char* rb = smem + ((nsteps - 1) & 1) * 65536;
        HALFSTEP(rb, 0, {}, 0);
        HALFSTEP(rb, 1, {}, 0);
    }
#undef HALFSTEP

    asm volatile("s_nop 7\n\ts_nop 7");        // MFMA->VALU read hazard insurance

    // C/D layout (32x32): col = lane&31, row = (r&3) + 8*(r>>2) + 4*(lane>>5)
    #pragma unroll
    for (int m = 0; m < 4; ++m){
        #pragma unroll
        for (int n = 0; n < 2; ++n){
            const int grb = m0 + wr * 128 + m * 32;
            const int gc  = n0 + wc * 64  + n * 32 + l31;
            #pragma unroll
            for (int r = 0; r < 16; ++r){
                const int row = (r & 3) + 8 * (r >> 2) + 4 * hg;
                if (EPI == 1){
                    Wout[(size_t)(grb + row) * ldw + gc] =
                        f2bf(__expf(10.0f * acc[m][n][r] - 10.0f));
                } else {
                    Fout[(size_t)(grb + row) * ldo + gc] =
                        Cadd[(size_t)(grb + row) * ldo + gc] + acc[m][n][r];
                }
            }
        }
    }
}

// ---------------------------------------------------------------------------
extern "C" void kernel_launch(void* const* d_in, const int* in_sizes, int n_in,
                              void* d_out, int out_size, void* d_ws, size_t ws_size,
                              hipStream_t stream)
{
    (void)n_in; (void)out_size;
    const float* inp = (const float*)d_in[0];
    const float* pos = (const float*)d_in[1];
    const float* off = (const float*)d_in[2];
    float* out = (float*)d_out;

    const int D = 1024, C = 2048;
    const int N = in_sizes[0] / D;            // 32768

    // workspace layout: b_bf[C*D] | offt[D*C] | a_bf[Mc*D] | w_buf[Mc*C]  (all bf16)
    unsigned short* b_bf = (unsigned short*)d_ws;
    unsigned short* offt = b_bf + (size_t)C * D;
    unsigned short* a_bf = offt + (size_t)D * C;
    size_t fixed = (size_t)C * D * 2 * 2;
    size_t avail = ws_size > fixed ? ws_size - fixed : 0;
    int Mc = 256;
    for (int cand = N; cand >= 256; cand >>= 1){
        if ((size_t)cand * (size_t)(D + C) * 2 <= avail){ Mc = cand; break; }
    }
    if (Mc > N) Mc = N;
    unsigned short* w_buf = a_bf + (size_t)Mc * D;

    hipFuncSetAttribute(reinterpret_cast<const void*>(&gemm256<1>),
                        hipFuncAttributeMaxDynamicSharedMemorySize, 131072);
    hipFuncSetAttribute(reinterpret_cast<const void*>(&gemm256<2>),
                        hipFuncAttributeMaxDynamicSharedMemorySize, 131072);

    float* reg_out = out + (size_t)N * D;
    hipMemsetAsync(reg_out, 0, sizeof(float), stream);

    transpose_off<<<dim3(C / 64, D / 64), 256, 0, stream>>>(off, offt, reg_out);
    norm_rows_bf16<<<C, 256, 0, stream>>>(pos, b_bf);

    for (int r0 = 0; r0 < N; r0 += Mc){
        norm_rows_bf16<<<Mc, 256, 0, stream>>>(inp + (size_t)r0 * D, a_bf);
        // GEMM1: W[Mc][C] = exp(10 * (a . b^T) - 10)
        gemm256<1><<<dim3(Mc / 256, C / 256), 512, 131072, stream>>>(
            a_bf, D, b_bf, D, D, w_buf, C, nullptr, nullptr, 0);
        // GEMM2: out[Mc][D] = inp + W . offt^T
        gemm256<2><<<dim3(Mc / 256, D / 256), 512, 131072, stream>>>(
            w_buf, C, offt, C, C, nullptr, 0, inp + (size_t)r0 * D, out + (size_t)r0 * D, D);
    }
    norm_rows_f32<<<N, 256, 0, stream>>>(out);
}

// Round 5
// 398.409 us; speedup vs baseline: 1.1420x; 1.1420x over previous
//
#include <hip/hip_runtime.h>

typedef float  f32x4 __attribute__((ext_vector_type(4)));
typedef short  s16x8 __attribute__((ext_vector_type(8)));
typedef unsigned short u16x4 __attribute__((ext_vector_type(4)));

#define AS1 __attribute__((address_space(1)))
#define AS3 __attribute__((address_space(3)))

__device__ __forceinline__ unsigned short f2bf(float x){
    union { float f; unsigned int u; } v; v.f = x;
    unsigned int r = v.u + 0x7FFFu + ((v.u >> 16) & 1u);   // RNE
    return (unsigned short)(r >> 16);
}

__device__ __forceinline__ void gload16(const unsigned short* g, const char* l){
    __builtin_amdgcn_global_load_lds((const AS1 void*)g, (AS3 void*)l, 16, 0, 0);
}

__device__ __forceinline__ void mfma16(f32x4& c, s16x8 a, s16x8 b){
    asm volatile("v_mfma_f32_16x16x32_bf16 %0, %1, %2, %0" : "+v"(c) : "v"(a), "v"(b));
}

// barrier with compiler memory fence; NO lgkmcnt(0), NO sched_barrier(0):
// frag reads are plain IR loads, so the compiler emits counted lgkmcnt
// before the first consuming MFMA (m97 pattern) instead of a full drain.
#define GBAR() do{ asm volatile("" ::: "memory"); __builtin_amdgcn_s_barrier(); \
                   asm volatile("" ::: "memory"); }while(0)
#define VMW(N) asm volatile("s_waitcnt vmcnt(" #N ")" ::: "memory")

// ---------------------------------------------------------------------------
// Row l2-normalize [rows][1024] f32 -> bf16. One 256-thread block per row.
// ---------------------------------------------------------------------------
__global__ __launch_bounds__(256) void norm_rows_bf16(const float* __restrict__ in,
                                                      unsigned short* __restrict__ out){
    const int row = blockIdx.x;
    const int t   = threadIdx.x;
    f32x4 x = ((const f32x4*)(in + (size_t)row * 1024))[t];
    float ss = x[0]*x[0] + x[1]*x[1] + x[2]*x[2] + x[3]*x[3];
    #pragma unroll
    for (int o = 32; o > 0; o >>= 1) ss += __shfl_xor(ss, o);
    __shared__ float red[4];
    if ((t & 63) == 0) red[t >> 6] = ss;
    __syncthreads();
    float tot = red[0] + red[1] + red[2] + red[3];
    float inv = 1.0f / fmaxf(sqrtf(tot), 1e-12f);
    u16x4 o;
    #pragma unroll
    for (int j = 0; j < 4; ++j) o[j] = f2bf(x[j] * inv);
    ((u16x4*)(out + (size_t)row * 1024))[t] = o;
}

// ---------------------------------------------------------------------------
// Final in-place row l2-normalize of d_out [N][1024] f32.
// ---------------------------------------------------------------------------
__global__ __launch_bounds__(256) void norm_rows_f32(float* __restrict__ buf){
    const int row = blockIdx.x;
    const int t   = threadIdx.x;
    f32x4* p = (f32x4*)(buf + (size_t)row * 1024);
    f32x4 x = p[t];
    float ss = x[0]*x[0] + x[1]*x[1] + x[2]*x[2] + x[3]*x[3];
    #pragma unroll
    for (int o = 32; o > 0; o >>= 1) ss += __shfl_xor(ss, o);
    __shared__ float red[4];
    if ((t & 63) == 0) red[t >> 6] = ss;
    __syncthreads();
    float tot = red[0] + red[1] + red[2] + red[3];
    float inv = 1.0f / fmaxf(sqrtf(tot), 1e-12f);
    p[t] = x * inv;
}

// ---------------------------------------------------------------------------
// offset [C=2048][D=1024] f32 -> offt [D][C] bf16 (LDS-tiled transpose),
// fused sum(offset^2) -> atomicAdd(reg_out). Tile: 64(c) x 64(d).
// ---------------------------------------------------------------------------
__global__ __launch_bounds__(256) void transpose_off(const float* __restrict__ off,
                                                     unsigned short* __restrict__ offt,
                                                     float* __restrict__ reg_out){
    __shared__ unsigned short t_lds[64][68];   // [d][c], padded row
    const int t  = threadIdx.x;
    const int c0 = blockIdx.x * 64;
    const int d0 = blockIdx.y * 64;
    float ss = 0.f;
    #pragma unroll
    for (int p = 0; p < 4; ++p){
        int c  = p * 16 + (t >> 4);
        int dq = t & 15;
        f32x4 v = *(const f32x4*)(off + (size_t)(c0 + c) * 1024 + d0 + dq * 4);
        ss += v[0]*v[0] + v[1]*v[1] + v[2]*v[2] + v[3]*v[3];
        #pragma unroll
        for (int j = 0; j < 4; ++j) t_lds[dq * 4 + j][c] = f2bf(v[j]);
    }
    __syncthreads();
    #pragma unroll
    for (int p = 0; p < 4; ++p){
        int d  = p * 16 + (t >> 4);
        int cq = t & 15;
        u16x4 o = *(const u16x4*)&t_lds[d][cq * 4];
        *(u16x4*)(offt + (size_t)(d0 + d) * 2048 + c0 + cq * 4) = o;
    }
    #pragma unroll
    for (int o = 32; o > 0; o >>= 1) ss += __shfl_xor(ss, o);
    __shared__ float red[4];
    if ((t & 63) == 0) red[t >> 6] = ss;
    __syncthreads();
    if (t == 0) atomicAdd(reg_out, red[0] + red[1] + red[2] + red[3]);
}

// ---------------------------------------------------------------------------
// GEMM: acc[m][n] = sum_k A[m][k] * B[n][k]   (both bf16, K-contiguous rows)
// 256x256 tile, BK=64, 512 threads (8 waves, 2Mx4N; wave tile 128x64).
// 16x16x32 bf16 MFMA. Double-buffered 128 KiB LDS; buffer = [Ak0|Bk0|Ak1|Bk1]
// 16KB quarters (256 rows x 32 k, 64B rows, XOR granule swizzle
// g ^= (row>>1)&3 via pre-swizzled global source + swizzled ds_read;
// measured 0 conflicts in r2/r3). 4 phases / K-tile, m201 shape:
//   {4-8 ds_read | stage 1 quarter(t+1)} -> barrier -> 16 MFMA
//   (compiler-counted lgkmcnt) -> [vmcnt(4) at P1,P3] -> barrier
// Loads stay in flight across barriers; vmcnt never 0 in steady state.
// Bijective XCD swizzle: by-fastest within each XCD's contiguous chunk.
// EPI==1: Wout[m][n] = bf16(exp(10*acc - 10))        (ld = ldw)
// EPI==2: Fout[m][n] = Cadd[m][n] + acc              (ld = ldo)
// ---------------------------------------------------------------------------
template<int EPI>
__global__ __launch_bounds__(512, 2)
void gemm256(const unsigned short* __restrict__ A, int lda,
             const unsigned short* __restrict__ B, int ldb,
             int K,
             unsigned short* __restrict__ Wout, int ldw,
             const float* __restrict__ Cadd, float* __restrict__ Fout, int ldo)
{
    extern __shared__ char smem[];             // 2 x 64 KiB
    const int tid  = threadIdx.x;

    // ---- XCD-aware bijective remap (8 XCDs; L2 locality on A panels) ----
    int bx = blockIdx.x, by = blockIdx.y;
    {
        const int gx = gridDim.x, gy = gridDim.y;
        const int nwg = gx * gy;
        if ((nwg & 7) == 0){
            const int lid = bx + gx * by;
            const int q   = nwg >> 3;
            const int n   = (lid & 7) * q + (lid >> 3);
            const int sh  = 31 - __clz(gy);    // gy is a power of two here
            bx = n >> sh;
            by = n & (gy - 1);
        }
    }
    const int m0   = bx * 256;
    const int n0   = by * 256;
    const int wid  = tid >> 6, lane = tid & 63;
    const int wr   = wid >> 2, wc = wid & 3;   // 2 x 4 waves, wave tile 128x64
    const int kg   = lane >> 4, r16 = lane & 15;

    // ---- staging: per 16KB quarter, thread covers phys bytes tid*16 and
    // 8192+tid*16; phys granule (tid&3) at row tid>>2 (and +128) holds
    // logical granule (tid&3)^((row>>1)&3) -> pre-swizzled global source.
    const int srow = tid >> 2;
    const int sg   = (tid & 3) ^ ((tid >> 3) & 3);
    const unsigned short* sA0 = A + (size_t)(m0 + srow)       * lda + sg * 8;
    const unsigned short* sA1 = A + (size_t)(m0 + 128 + srow) * lda + sg * 8;
    const unsigned short* sB0 = B + (size_t)(n0 + srow)       * ldb + sg * 8;
    const unsigned short* sB1 = B + (size_t)(n0 + 128 + srow) * ldb + sg * 8;
    const int lp0 = tid * 16, lp1 = 8192 + tid * 16;

    auto stageA = [&](char* wb, int blk, int ke){
        gload16(sA0 + ke, wb + blk * 16384 + lp0);
        gload16(sA1 + ke, wb + blk * 16384 + lp1);
    };
    auto stageB = [&](char* wb, int blk, int ke){
        gload16(sB0 + ke, wb + blk * 16384 + lp0);
        gload16(sB1 + ke, wb + blk * 16384 + lp1);
    };

    // ---- ds_read fragment offsets within a K-half (quarter pair); swizzled.
    // Wave reads 16 rows x all 4 granules = contiguous 1024B => 0 conflicts.
    int aoff[8], boff[4];
    #pragma unroll
    for (int m = 0; m < 8; ++m){
        int row = wr * 128 + m * 16 + r16;
        aoff[m] = row * 64 + ((kg ^ ((row >> 1) & 3)) << 4);
    }
    #pragma unroll
    for (int n = 0; n < 4; ++n){
        int row = wc * 64 + n * 16 + r16;
        boff[n] = 16384 + row * 64 + ((kg ^ ((row >> 1) & 3)) << 4);
    }

    f32x4 acc[8][4] = {};
    const int nsteps = K >> 6;                 // BK = 64

    // ---- prologue: stage tile 0 fully; wait quarters 0,1 ----
    {
        char* wb = smem;
        stageA(wb, 0, 0);  stageB(wb, 1, 0);
        stageA(wb, 2, 32); stageB(wb, 3, 32);
    }
    VMW(4);
    GBAR();

#define RD_A(dst, hb, mb) { _Pragma("unroll") for (int m = 0; m < 4; ++m) \
    dst[m] = *(const s16x8*)((hb) + aoff[(mb) + m]); }
#define RD_B(dst, hb)     { _Pragma("unroll") for (int n = 0; n < 4; ++n) \
    dst[n] = *(const s16x8*)((hb) + boff[n]); }
#define MFMA16X(mb, av, bv) { __builtin_amdgcn_s_setprio(1); \
    _Pragma("unroll") for (int m = 0; m < 4; ++m) \
    _Pragma("unroll") for (int n = 0; n < 4; ++n) \
        mfma16(acc[(mb) + m][n], av[m], bv[n]); \
    __builtin_amdgcn_s_setprio(0); }

    s16x8 a[4], b[4];

    #pragma unroll 1
    for (int t = 0; t < nsteps - 1; ++t){
        const char* rb = smem + (t & 1) * 65536;
        char*       wb = smem + ((t + 1) & 1) * 65536;
        const int   ke = (t + 1) * 64;
        const char* h0 = rb;                   // K-half 0 (quarters 0,1)
        const char* h1 = rb + 32768;           // K-half 1 (quarters 2,3)
        // P0: reads ks0 {A m0-3, B}; stage Q0(t+1)
        RD_A(a, h0, 0); RD_B(b, h0);
        stageA(wb, 0, ke);
        GBAR();
        MFMA16X(0, a, b);
        GBAR();
        // P1: reads ks0 {A m4-7}; stage Q1(t+1); vmcnt: Q2,Q3(t) landed
        RD_A(a, h0, 4);
        stageB(wb, 1, ke);
        GBAR();
        MFMA16X(4, a, b);
        VMW(4);
        GBAR();
        // P2: reads ks1 {A m0-3, B}; stage Q2(t+1)
        RD_A(a, h1, 0); RD_B(b, h1);
        stageA(wb, 2, ke + 32);
        GBAR();
        MFMA16X(0, a, b);
        GBAR();
        // P3: reads ks1 {A m4-7}; stage Q3(t+1); vmcnt: Q0,Q1(t+1) landed
        RD_A(a, h1, 4);
        stageB(wb, 3, ke + 32);
        GBAR();
        MFMA16X(4, a, b);
        VMW(4);
        GBAR();
    }
    {   // ---- last K-tile: no staging; full drain before ks1 reads ----
        const char* rb = smem + ((nsteps - 1) & 1) * 65536;
        const char* h0 = rb;
        const char* h1 = rb + 32768;
        RD_A(a, h0, 0); RD_B(b, h0);
        GBAR();
        MFMA16X(0, a, b);
        GBAR();
        RD_A(a, h0, 4);
        GBAR();
        MFMA16X(4, a, b);
        VMW(0);
        GBAR();
        RD_A(a, h1, 0); RD_B(b, h1);
        GBAR();
        MFMA16X(0, a, b);
        GBAR();
        RD_A(a, h1, 4);
        GBAR();
        MFMA16X(4, a, b);
    }
#undef RD_A
#undef RD_B
#undef MFMA16X

    asm volatile("s_nop 7\n\ts_nop 7");        // MFMA->VALU read hazard insurance

    const int crow = (lane >> 4) * 4;          // C/D: row = (lane>>4)*4 + reg
    const int ccol = lane & 15;                //      col = lane & 15

    #pragma unroll
    for (int m = 0; m < 8; ++m){
        #pragma unroll
        for (int n = 0; n < 4; ++n){
            const int gr = m0 + wr * 128 + m * 16 + crow;
            const int gc = n0 + wc * 64  + n * 16 + ccol;
            if (EPI == 1){
                #pragma unroll
                for (int r = 0; r < 4; ++r){
                    float sv = acc[m][n][r];
                    Wout[(size_t)(gr + r) * ldw + gc] = f2bf(__expf(10.0f * sv - 10.0f));
                }
            } else {
                #pragma unroll
                for (int r = 0; r < 4; ++r){
                    Fout[(size_t)(gr + r) * ldo + gc] =
                        Cadd[(size_t)(gr + r) * ldo + gc] + acc[m][n][r];
                }
            }
        }
    }
}

// ---------------------------------------------------------------------------
extern "C" void kernel_launch(void* const* d_in, const int* in_sizes, int n_in,
                              void* d_out, int out_size, void* d_ws, size_t ws_size,
                              hipStream_t stream)
{
    (void)n_in; (void)out_size;
    const float* inp = (const float*)d_in[0];
    const float* pos = (const float*)d_in[1];
    const float* off = (const float*)d_in[2];
    float* out = (float*)d_out;

    const int D = 1024, C = 2048;
    const int N = in_sizes[0] / D;            // 32768

    // workspace layout: b_bf[C*D] | offt[D*C] | a_bf[Mc*D] | w_buf[Mc*C]  (all bf16)
    unsigned short* b_bf = (unsigned short*)d_ws;
    unsigned short* offt = b_bf + (size_t)C * D;
    unsigned short* a_bf = offt + (size_t)D * C;
    size_t fixed = (size_t)C * D * 2 * 2;
    size_t avail = ws_size > fixed ? ws_size - fixed : 0;
    int Mc = 256;
    for (int cand = N; cand >= 256; cand >>= 1){
        if ((size_t)cand * (size_t)(D + C) * 2 <= avail){ Mc = cand; break; }
    }
    if (Mc > N) Mc = N;
    unsigned short* w_buf = a_bf + (size_t)Mc * D;

    hipFuncSetAttribute(reinterpret_cast<const void*>(&gemm256<1>),
                        hipFuncAttributeMaxDynamicSharedMemorySize, 131072);
    hipFuncSetAttribute(reinterpret_cast<const void*>(&gemm256<2>),
                        hipFuncAttributeMaxDynamicSharedMemorySize, 131072);

    float* reg_out = out + (size_t)N * D;
    hipMemsetAsync(reg_out, 0, sizeof(float), stream);

    transpose_off<<<dim3(C / 64, D / 64), 256, 0, stream>>>(off, offt, reg_out);
    norm_rows_bf16<<<C, 256, 0, stream>>>(pos, b_bf);

    for (int r0 = 0; r0 < N; r0 += Mc){
        norm_rows_bf16<<<Mc, 256, 0, stream>>>(inp + (size_t)r0 * D, a_bf);
        // GEMM1: W[Mc][C] = exp(10 * (a . b^T) - 10)
        gemm256<1><<<dim3(Mc / 256, C / 256), 512, 131072, stream>>>(
            a_bf, D, b_bf, D, D, w_buf, C, nullptr, nullptr, 0);
        // GEMM2: out[Mc][D] = inp + W . offt^T
        gemm256<2><<<dim3(Mc / 256, D / 256), 512, 131072, stream>>>(
            w_buf, C, offt, C, C, nullptr, 0, inp + (size_t)r0 * D, out + (size_t)r0 * D, D);
    }
    norm_rows_f32<<<N, 256, 0, stream>>>(out);
}

// Round 6
// 391.566 us; speedup vs baseline: 1.1619x; 1.0175x over previous
//
#include <hip/hip_runtime.h>

typedef float  f32x4 __attribute__((ext_vector_type(4)));
typedef short  s16x8 __attribute__((ext_vector_type(8)));
typedef unsigned short u16x4 __attribute__((ext_vector_type(4)));

#define AS1 __attribute__((address_space(1)))
#define AS3 __attribute__((address_space(3)))

__device__ __forceinline__ unsigned short f2bf(float x){
    union { float f; unsigned int u; } v; v.f = x;
    unsigned int r = v.u + 0x7FFFu + ((v.u >> 16) & 1u);   // RNE
    return (unsigned short)(r >> 16);
}

__device__ __forceinline__ void gload16(const unsigned short* g, const char* l){
    __builtin_amdgcn_global_load_lds((const AS1 void*)g, (AS3 void*)l, 16, 0, 0);
}

__device__ __forceinline__ void mfma16(f32x4& c, s16x8 a, s16x8 b){
    asm volatile("v_mfma_f32_16x16x32_bf16 %0, %1, %2, %0" : "+v"(c) : "v"(a), "v"(b));
}

#define GBAR() do{ asm volatile("" ::: "memory"); __builtin_amdgcn_s_barrier(); \
                   asm volatile("" ::: "memory"); }while(0)
#define VMW(N)  asm volatile("s_waitcnt vmcnt(" #N ")" ::: "memory")
#define LGKM0() asm volatile("s_waitcnt lgkmcnt(0)" ::: "memory")

// ---------------------------------------------------------------------------
// Row l2-normalize [rows][1024] f32 -> bf16. One 256-thread block per row.
// ---------------------------------------------------------------------------
__global__ __launch_bounds__(256) void norm_rows_bf16(const float* __restrict__ in,
                                                      unsigned short* __restrict__ out){
    const int row = blockIdx.x;
    const int t   = threadIdx.x;
    f32x4 x = ((const f32x4*)(in + (size_t)row * 1024))[t];
    float ss = x[0]*x[0] + x[1]*x[1] + x[2]*x[2] + x[3]*x[3];
    #pragma unroll
    for (int o = 32; o > 0; o >>= 1) ss += __shfl_xor(ss, o);
    __shared__ float red[4];
    if ((t & 63) == 0) red[t >> 6] = ss;
    __syncthreads();
    float tot = red[0] + red[1] + red[2] + red[3];
    float inv = 1.0f / fmaxf(sqrtf(tot), 1e-12f);
    u16x4 o;
    #pragma unroll
    for (int j = 0; j < 4; ++j) o[j] = f2bf(x[j] * inv);
    ((u16x4*)(out + (size_t)row * 1024))[t] = o;
}

// ---------------------------------------------------------------------------
// Final in-place row l2-normalize of d_out [N][1024] f32.
// ---------------------------------------------------------------------------
__global__ __launch_bounds__(256) void norm_rows_f32(float* __restrict__ buf){
    const int row = blockIdx.x;
    const int t   = threadIdx.x;
    f32x4* p = (f32x4*)(buf + (size_t)row * 1024);
    f32x4 x = p[t];
    float ss = x[0]*x[0] + x[1]*x[1] + x[2]*x[2] + x[3]*x[3];
    #pragma unroll
    for (int o = 32; o > 0; o >>= 1) ss += __shfl_xor(ss, o);
    __shared__ float red[4];
    if ((t & 63) == 0) red[t >> 6] = ss;
    __syncthreads();
    float tot = red[0] + red[1] + red[2] + red[3];
    float inv = 1.0f / fmaxf(sqrtf(tot), 1e-12f);
    p[t] = x * inv;
}

// ---------------------------------------------------------------------------
// offset [C=2048][D=1024] f32 -> offt [D][C] bf16 (LDS-tiled transpose),
// fused sum(offset^2) -> atomicAdd(reg_out). Tile: 64(c) x 64(d).
// ---------------------------------------------------------------------------
__global__ __launch_bounds__(256) void transpose_off(const float* __restrict__ off,
                                                     unsigned short* __restrict__ offt,
                                                     float* __restrict__ reg_out){
    __shared__ unsigned short t_lds[64][68];   // [d][c], padded row
    const int t  = threadIdx.x;
    const int c0 = blockIdx.x * 64;
    const int d0 = blockIdx.y * 64;
    float ss = 0.f;
    #pragma unroll
    for (int p = 0; p < 4; ++p){
        int c  = p * 16 + (t >> 4);
        int dq = t & 15;
        f32x4 v = *(const f32x4*)(off + (size_t)(c0 + c) * 1024 + d0 + dq * 4);
        ss += v[0]*v[0] + v[1]*v[1] + v[2]*v[2] + v[3]*v[3];
        #pragma unroll
        for (int j = 0; j < 4; ++j) t_lds[dq * 4 + j][c] = f2bf(v[j]);
    }
    __syncthreads();
    #pragma unroll
    for (int p = 0; p < 4; ++p){
        int d  = p * 16 + (t >> 4);
        int cq = t & 15;
        u16x4 o = *(const u16x4*)&t_lds[d][cq * 4];
        *(u16x4*)(offt + (size_t)(d0 + d) * 2048 + c0 + cq * 4) = o;
    }
    #pragma unroll
    for (int o = 32; o > 0; o >>= 1) ss += __shfl_xor(ss, o);
    __shared__ float red[4];
    if ((t & 63) == 0) red[t >> 6] = ss;
    __syncthreads();
    if (t == 0) atomicAdd(reg_out, red[0] + red[1] + red[2] + red[3]);
}

// ---------------------------------------------------------------------------
// GEMM: acc[m][n] = sum_k A[m][k] * B[n][k]   (both bf16, K-contiguous rows)
// 256x256 tile, BK=64, 512 threads (8 waves, 2Mx4N; wave tile 128x64).
// 16x16x32 bf16 MFMA. Double-buffered 128 KiB LDS; buffer = [Ak0|Bk0|Ak1|Bk1]
// 16KB quarters (256 rows x 32 k, 64B rows, XOR granule swizzle
// g ^= (row>>1)&3 via pre-swizzled global source + swizzled ds_read; 0
// conflicts measured). 4 phases / K-tile, ONE barrier per phase; staging
// issued AFTER the barrier (in the MFMA shadow):
//   P(p): reads(p) -> [vmcnt] -> barrier -> stage quarter(t+1) -> lgkmcnt(0)
//         -> setprio(1) + 16 MFMA + setprio(0)
// Race-free: stage(t+1) issues only after GBAR(t,P0); all waves reached it
// only after issuing MFMA(t-1,P3), whose lgkmcnt(0) proves their tile-(t-1)
// reads of that buffer COMPLETED. Reads(t,P0/P2) protected by vmcnt(2)+GBAR
// at the preceding P3/P1 (ledger: 3 quarters = 6 loads outstanding, drain 2).
// EPI==1: Wout[m][n] = bf16(exp(10*acc - 10))        (ld = ldw)
// EPI==2: Fout[m][n] = Cadd[m][n] + acc              (ld = ldo)
// ---------------------------------------------------------------------------
template<int EPI>
__global__ __launch_bounds__(512, 2)
void gemm256(const unsigned short* __restrict__ A, int lda,
             const unsigned short* __restrict__ B, int ldb,
             int K,
             unsigned short* __restrict__ Wout, int ldw,
             const float* __restrict__ Cadd, float* __restrict__ Fout, int ldo)
{
    extern __shared__ char smem[];             // 2 x 64 KiB
    const int tid  = threadIdx.x;

    // ---- XCD-aware bijective remap (8 XCDs; L2 locality on A panels) ----
    int bx = blockIdx.x, by = blockIdx.y;
    {
        const int gx = gridDim.x, gy = gridDim.y;
        const int nwg = gx * gy;
        if ((nwg & 7) == 0){
            const int lid = bx + gx * by;
            const int q   = nwg >> 3;
            const int n   = (lid & 7) * q + (lid >> 3);
            const int sh  = 31 - __clz(gy);    // gy is a power of two here
            bx = n >> sh;
            by = n & (gy - 1);
        }
    }
    const int m0   = bx * 256;
    const int n0   = by * 256;
    const int wid  = tid >> 6, lane = tid & 63;
    const int wr   = wid >> 2, wc = wid & 3;   // 2 x 4 waves, wave tile 128x64
    const int kg   = lane >> 4, r16 = lane & 15;

    // ---- staging: per 16KB quarter, thread covers phys bytes tid*16 and
    // 8192+tid*16; phys granule (tid&3) at row tid>>2 (and +128) holds
    // logical granule (tid&3)^((row>>1)&3) -> pre-swizzled global source.
    const int srow = tid >> 2;
    const int sg   = (tid & 3) ^ ((tid >> 3) & 3);
    const unsigned short* sA0 = A + (size_t)(m0 + srow)       * lda + sg * 8;
    const unsigned short* sA1 = A + (size_t)(m0 + 128 + srow) * lda + sg * 8;
    const unsigned short* sB0 = B + (size_t)(n0 + srow)       * ldb + sg * 8;
    const unsigned short* sB1 = B + (size_t)(n0 + 128 + srow) * ldb + sg * 8;
    const int lp0 = tid * 16, lp1 = 8192 + tid * 16;

    auto stageA = [&](char* wb, int blk, int ke){
        gload16(sA0 + ke, wb + blk * 16384 + lp0);
        gload16(sA1 + ke, wb + blk * 16384 + lp1);
    };
    auto stageB = [&](char* wb, int blk, int ke){
        gload16(sB0 + ke, wb + blk * 16384 + lp0);
        gload16(sB1 + ke, wb + blk * 16384 + lp1);
    };

    // ---- ds_read fragment offsets within a K-half (quarter pair); swizzled.
    // Wave reads 16 rows x all 4 granules = contiguous 1024B => 0 conflicts.
    int aoff[8], boff[4];
    #pragma unroll
    for (int m = 0; m < 8; ++m){
        int row = wr * 128 + m * 16 + r16;
        aoff[m] = row * 64 + ((kg ^ ((row >> 1) & 3)) << 4);
    }
    #pragma unroll
    for (int n = 0; n < 4; ++n){
        int row = wc * 64 + n * 16 + r16;
        boff[n] = 16384 + row * 64 + ((kg ^ ((row >> 1) & 3)) << 4);
    }

    f32x4 acc[8][4] = {};
    const int nsteps = K >> 6;                 // BK = 64

    // ---- prologue: stage tile 0 fully (Q0..Q3 = 8 loads); wait Q0,Q1 ----
    {
        char* wb = smem;
        stageA(wb, 0, 0);  stageB(wb, 1, 0);
        stageA(wb, 2, 32); stageB(wb, 3, 32);
    }
    VMW(4);
    GBAR();

#define RD_A(dst, hb, mb) { _Pragma("unroll") for (int m = 0; m < 4; ++m) \
    dst[m] = *(const s16x8*)((hb) + aoff[(mb) + m]); }
#define RD_B(dst, hb)     { _Pragma("unroll") for (int n = 0; n < 4; ++n) \
    dst[n] = *(const s16x8*)((hb) + boff[n]); }
#define MFMA16X(mb, av, bv) { __builtin_amdgcn_s_setprio(1); \
    _Pragma("unroll") for (int m = 0; m < 4; ++m) \
    _Pragma("unroll") for (int n = 0; n < 4; ++n) \
        mfma16(acc[(mb) + m][n], av[m], bv[n]); \
    __builtin_amdgcn_s_setprio(0); }

    s16x8 a[4], a2[4], b[4];

    #pragma unroll 1
    for (int t = 0; t < nsteps - 1; ++t){
        const char* rb = smem + (t & 1) * 65536;
        char*       wb = smem + ((t + 1) & 1) * 65536;
        const int   ke = (t + 1) * 64;
        const char* h0 = rb;                   // quarters Q0(A),Q1(B): k 0-31
        const char* h1 = rb + 32768;           // quarters Q2(A),Q3(B): k 32-63
        // P0
        RD_A(a, h0, 0); RD_B(b, h0);
        GBAR();
        stageA(wb, 0, ke);                     // Q0(t+1)
        LGKM0();
        MFMA16X(0, a, b);
        // P1
        RD_A(a2, h0, 4);
        VMW(2);                                // drain Q2,Q3(t); keep Q0(t+1)
        GBAR();
        stageB(wb, 1, ke);                     // Q1(t+1)
        LGKM0();
        MFMA16X(4, a2, b);
        // P2
        RD_A(a, h1, 0); RD_B(b, h1);
        GBAR();
        stageA(wb, 2, ke + 32);                // Q2(t+1)
        LGKM0();
        MFMA16X(0, a, b);
        // P3
        RD_A(a2, h1, 4);
        VMW(2);                                // drain Q0,Q1(t+1); keep Q2(t+1)
        GBAR();
        stageB(wb, 3, ke + 32);                // Q3(t+1)
        LGKM0();
        MFMA16X(4, a2, b);
    }
    {   // ---- last tile: no staging; drain Q2,Q3(last) before P2 reads ----
        const char* rb = smem + ((nsteps - 1) & 1) * 65536;
        const char* h0 = rb;
        const char* h1 = rb + 32768;
        RD_A(a, h0, 0); RD_B(b, h0);
        GBAR();
        LGKM0();
        MFMA16X(0, a, b);
        RD_A(a2, h0, 4);
        VMW(0);
        GBAR();
        LGKM0();
        MFMA16X(4, a2, b);
        RD_A(a, h1, 0); RD_B(b, h1);
        GBAR();
        LGKM0();
        MFMA16X(0, a, b);
        RD_A(a2, h1, 4);
        GBAR();
        LGKM0();
        MFMA16X(4, a2, b);
    }
#undef RD_A
#undef RD_B
#undef MFMA16X

    asm volatile("s_nop 7\n\ts_nop 7");        // MFMA->VALU read hazard insurance

    const int crow = (lane >> 4) * 4;          // C/D: row = (lane>>4)*4 + reg
    const int ccol = lane & 15;                //      col = lane & 15

    #pragma unroll
    for (int m = 0; m < 8; ++m){
        #pragma unroll
        for (int n = 0; n < 4; ++n){
            const int gr = m0 + wr * 128 + m * 16 + crow;
            const int gc = n0 + wc * 64  + n * 16 + ccol;
            if (EPI == 1){
                #pragma unroll
                for (int r = 0; r < 4; ++r){
                    float sv = acc[m][n][r];
                    Wout[(size_t)(gr + r) * ldw + gc] = f2bf(__expf(10.0f * sv - 10.0f));
                }
            } else {
                #pragma unroll
                for (int r = 0; r < 4; ++r){
                    Fout[(size_t)(gr + r) * ldo + gc] =
                        Cadd[(size_t)(gr + r) * ldo + gc] + acc[m][n][r];
                }
            }
        }
    }
}

// ---------------------------------------------------------------------------
extern "C" void kernel_launch(void* const* d_in, const int* in_sizes, int n_in,
                              void* d_out, int out_size, void* d_ws, size_t ws_size,
                              hipStream_t stream)
{
    (void)n_in; (void)out_size;
    const float* inp = (const float*)d_in[0];
    const float* pos = (const float*)d_in[1];
    const float* off = (const float*)d_in[2];
    float* out = (float*)d_out;

    const int D = 1024, C = 2048;
    const int N = in_sizes[0] / D;            // 32768

    // workspace layout: b_bf[C*D] | offt[D*C] | a_bf[Mc*D] | w_buf[Mc*C]  (all bf16)
    unsigned short* b_bf = (unsigned short*)d_ws;
    unsigned short* offt = b_bf + (size_t)C * D;
    unsigned short* a_bf = offt + (size_t)D * C;
    size_t fixed = (size_t)C * D * 2 * 2;
    size_t avail = ws_size > fixed ? ws_size - fixed : 0;
    int Mc = 256;
    for (int cand = N; cand >= 256; cand >>= 1){
        if ((size_t)cand * (size_t)(D + C) * 2 <= avail){ Mc = cand; break; }
    }
    if (Mc > N) Mc = N;
    unsigned short* w_buf = a_bf + (size_t)Mc * D;

    hipFuncSetAttribute(reinterpret_cast<const void*>(&gemm256<1>),
                        hipFuncAttributeMaxDynamicSharedMemorySize, 131072);
    hipFuncSetAttribute(reinterpret_cast<const void*>(&gemm256<2>),
                        hipFuncAttributeMaxDynamicSharedMemorySize, 131072);

    float* reg_out = out + (size_t)N * D;
    hipMemsetAsync(reg_out, 0, sizeof(float), stream);

    transpose_off<<<dim3(C / 64, D / 64), 256, 0, stream>>>(off, offt, reg_out);
    norm_rows_bf16<<<C, 256, 0, stream>>>(pos, b_bf);

    for (int r0 = 0; r0 < N; r0 += Mc){
        norm_rows_bf16<<<Mc, 256, 0, stream>>>(inp + (size_t)r0 * D, a_bf);
        // GEMM1: W[Mc][C] = exp(10 * (a . b^T) - 10)
        gemm256<1><<<dim3(Mc / 256, C / 256), 512, 131072, stream>>>(
            a_bf, D, b_bf, D, D, w_buf, C, nullptr, nullptr, 0);
        // GEMM2: out[Mc][D] = inp + W . offt^T
        gemm256<2><<<dim3(Mc / 256, D / 256), 512, 131072, stream>>>(
            w_buf, C, offt, C, C, nullptr, 0, inp + (size_t)r0 * D, out + (size_t)r0 * D, D);
    }
    norm_rows_f32<<<N, 256, 0, stream>>>(out);
}